// Round 8
// baseline (666.786 us; speedup 1.0000x reference)
//
#include <hip/hip_runtime.h>

#define VOCAB   50000
#define LDIM    8921
#define DDIM    300
#define DPAD    320
#define KSZ     10
#define BATCH   8
#define TSEQ    2048
#define PADL    9
#define TPRIME  2057
#define TPADDED 2066

typedef short s8v __attribute__((ext_vector_type(8)));   // 8 x bf16 bits
typedef float f4v __attribute__((ext_vector_type(4)));

__device__ inline unsigned short f2bf(float f) {
  union { float f; unsigned u; } v; v.f = f;
  unsigned r = v.u + 0x7FFF + ((v.u >> 16) & 1);
  return (unsigned short)(r >> 16);
}

// ---- K1: embedding gather -> xp_bf16[b][tau][DPAD], zero-padded rows/cols
__global__ __launch_bounds__(256) void gather_kernel(
    const int* __restrict__ ids, const float* __restrict__ embed_w,
    unsigned short* __restrict__ xp) {
  int wid = blockIdx.x * 4 + (threadIdx.x >> 6);
  int lane = threadIdx.x & 63;
  int b = wid / TPADDED, tau = wid % TPADDED;
  bool inr = (tau >= PADL) && (tau < PADL + TSEQ);
  int row = inr ? ids[b * TSEQ + (tau - PADL)] : 0;
  const float* src = embed_w + (size_t)row * DDIM;
  unsigned short* dst = xp + ((size_t)b * TPADDED + tau) * DPAD;
  for (int j = 0; j < 5; ++j) {
    int col = j * 64 + lane;
    float v = (inr && col < DDIM) ? src[col] : 0.0f;
    dst[col] = f2bf(v);
  }
}

// ---- K2: conv weight transform -> wT[k][o][i] bf16, o/i padded to 320 with 0
__global__ __launch_bounds__(256) void wt_kernel(
    const float* __restrict__ w, unsigned short* __restrict__ wT) {
  int k = blockIdx.x / DPAD, o = blockIdx.x % DPAD;
  for (int i = threadIdx.x; i < DPAD; i += 256) {
    float v = (o < DDIM && i < DDIM) ? w[((size_t)o * DDIM + i) * KSZ + k] : 0.0f;
    wT[((size_t)k * DPAD + o) * DPAD + i] = f2bf(v);
  }
}

// ---- K3: U transform -> Ub[l][d] bf16, l padded to 8960, d to 320 with 0
#define LPAD 8960
__global__ __launch_bounds__(256) void ut_kernel(
    const float* __restrict__ U, unsigned short* __restrict__ Ub) {
  int l = blockIdx.x;
  for (int d = threadIdx.x; d < DPAD; d += 256) {
    float v = (l < LDIM && d < DDIM) ? U[(size_t)l * DDIM + d] : 0.0f;
    Ub[(size_t)l * DPAD + d] = f2bf(v);
  }
}

// ---- K4: conv via MFMA. h[b][t][o] bf16, relu+bias.
// Round-3 shape restored: CTN=64, nf=4, double-buffered A, (256,2).
// wT traffic per block is fixed 2 MB -> bigger CTN halves per-XCD wT streaming.
#define CTN 64
#define CROWS 73          // CTN + KSZ - 1
#define CSTRIDE 336       // 0-conflict stride (verified round 7)
__global__ __launch_bounds__(256, 2) void conv_mfma_kernel(
    const unsigned short* __restrict__ xp, const unsigned short* __restrict__ wT,
    const float* __restrict__ bias, unsigned short* __restrict__ h) {
  __shared__ unsigned short xls[CROWS * CSTRIDE];   // 49056 B
  int b = blockIdx.x & 7, tb = blockIdx.x >> 3;
  int t0 = tb * CTN;
  int tid = threadIdx.x;
  {
    const unsigned short* src = xp + (size_t)b * TPADDED * DPAD;
    for (int idx = tid; idx < CROWS * (DPAD / 8); idx += 256) {
      int r = idx / 40, c8 = idx % 40;
      int tp = t0 + r;
      int4 v = make_int4(0, 0, 0, 0);
      if (tp < TPADDED) v = *(const int4*)&src[(size_t)tp * DPAD + c8 * 8];
      *(int4*)&xls[r * CSTRIDE + c8 * 8] = v;
    }
  }
  __syncthreads();
  int w = tid >> 6, lane = tid & 63;
  int l15 = lane & 15, quad = lane >> 4;
  f4v acc[5][4];
#pragma unroll
  for (int mf = 0; mf < 5; ++mf) {
    float bv[4];
#pragma unroll
    for (int r = 0; r < 4; ++r) {
      int o = w * 80 + mf * 16 + quad * 4 + r;
      bv[r] = (o < DDIM) ? bias[o] : 0.0f;
    }
#pragma unroll
    for (int nf = 0; nf < 4; ++nf) {
      acc[mf][nf][0] = bv[0]; acc[mf][nf][1] = bv[1];
      acc[mf][nf][2] = bv[2]; acc[mf][nf][3] = bv[3];
    }
  }
  s8v Acur[5], Anext[5];
#pragma unroll
  for (int mf = 0; mf < 5; ++mf)
    Acur[mf] = *(const s8v*)&wT[(size_t)(w * 80 + mf * 16 + l15) * DPAD + quad * 8];
  for (int iter = 0; iter < 100; ++iter) {
    int kc = iter / 10, it = iter % 10;
    if (iter < 99) {
      int kn = (iter + 1) / 10, itn = (iter + 1) % 10;
#pragma unroll
      for (int mf = 0; mf < 5; ++mf)
        Anext[mf] = *(const s8v*)&wT[((size_t)kn * DPAD + w * 80 + mf * 16 + l15) * DPAD + itn * 32 + quad * 8];
    }
    s8v Bv[4];
#pragma unroll
    for (int nf = 0; nf < 4; ++nf) {
      int rrow = nf * 16 + l15 + kc;
      Bv[nf] = *(const s8v*)&xls[rrow * CSTRIDE + it * 32 + quad * 8];
    }
#pragma unroll
    for (int mf = 0; mf < 5; ++mf)
#pragma unroll
      for (int nf = 0; nf < 4; ++nf)
        acc[mf][nf] = __builtin_amdgcn_mfma_f32_16x16x32_bf16(Acur[mf], Bv[nf], acc[mf][nf], 0, 0, 0);
#pragma unroll
    for (int mf = 0; mf < 5; ++mf) Acur[mf] = Anext[mf];
  }
#pragma unroll
  for (int mf = 0; mf < 5; ++mf) {
    int obase = w * 80 + mf * 16 + quad * 4;
#pragma unroll
    for (int nf = 0; nf < 4; ++nf) {
      int t = t0 + nf * 16 + l15;
      if (t < TPRIME) {
        unsigned short pk[4];
#pragma unroll
        for (int r = 0; r < 4; ++r) pk[r] = f2bf(fmaxf(acc[mf][nf][r], 0.0f));
        *(uint2*)&h[((size_t)b * TPRIME + t) * DPAD + obase] = *(uint2*)pk;
      }
    }
  }
}

// ---- K5: scores (U . h) via MFMA + fused softmax-weighted mean
// ALT=64 (4 mf), 4 t-quarter waves of 64l x 32t. BOTH operands depth-1
// prefetched (A from LDS, B from L2) so no load sits on the MFMA critical
// path. ~185 regs -> fits the verified (256,3)/192 no-spill budget.
#define ALT 64
#define ASTRIDE 336
#define NLB 140
#define ATT 128
__global__ __launch_bounds__(256, 3) void attn_mfma_kernel(
    const unsigned short* __restrict__ h, const unsigned short* __restrict__ Ub,
    const float* __restrict__ fcb, float* __restrict__ out) {
  __shared__ unsigned short uls[ALT * ASTRIDE];   // 43008 B
  int b = blockIdx.x & 7, lb = blockIdx.x >> 3;
  int l0 = lb * ALT;
  int tid = threadIdx.x;
  {
    const unsigned short* src = Ub + (size_t)l0 * DPAD;
    for (int idx = tid; idx < ALT * (DPAD / 8); idx += 256) {
      int r = idx / 40, c8 = idx % 40;
      *(int4*)&uls[r * ASTRIDE + c8 * 8] = *(const int4*)&src[(size_t)r * DPAD + c8 * 8];
    }
  }
  __syncthreads();
  int w = tid >> 6, lane = tid & 63;      // w = t-quarter
  int l15 = lane & 15, quad = lane >> 4;
  float se[4][4], sw[4][4];
#pragma unroll
  for (int mf = 0; mf < 4; ++mf)
#pragma unroll
    for (int r = 0; r < 4; ++r) { se[mf][r] = 0.0f; sw[mf][r] = 0.0f; }
  const unsigned short* hb = h + (size_t)b * TPRIME * DPAD;
  for (int t0 = 0; t0 < TPRIME; t0 += ATT) {
    int tg[2], tc[2];
#pragma unroll
    for (int nf = 0; nf < 2; ++nf) {
      tg[nf] = t0 + w * 32 + nf * 16 + l15;
      tc[nf] = (tg[nf] < TPRIME) ? tg[nf] : (TPRIME - 1);
    }
    f4v acc[4][2];
#pragma unroll
    for (int mf = 0; mf < 4; ++mf)
#pragma unroll
      for (int nf = 0; nf < 2; ++nf) {
        acc[mf][nf][0] = 0.0f; acc[mf][nf][1] = 0.0f;
        acc[mf][nf][2] = 0.0f; acc[mf][nf][3] = 0.0f;
      }
    s8v Acur[4], Anext[4], Bcur[2], Bnext[2];
#pragma unroll
    for (int nf = 0; nf < 2; ++nf)
      Bcur[nf] = *(const s8v*)&hb[(size_t)tc[nf] * DPAD + quad * 8];
#pragma unroll
    for (int mf = 0; mf < 4; ++mf)
      Acur[mf] = *(const s8v*)&uls[(mf * 16 + l15) * ASTRIDE + quad * 8];
    for (int kc = 0; kc < 10; ++kc) {
      if (kc < 9) {
        int koffn = (kc + 1) * 32 + quad * 8;
#pragma unroll
        for (int nf = 0; nf < 2; ++nf)
          Bnext[nf] = *(const s8v*)&hb[(size_t)tc[nf] * DPAD + koffn];
#pragma unroll
        for (int mf = 0; mf < 4; ++mf)
          Anext[mf] = *(const s8v*)&uls[(mf * 16 + l15) * ASTRIDE + koffn];
      }
#pragma unroll
      for (int mf = 0; mf < 4; ++mf)
#pragma unroll
        for (int nf = 0; nf < 2; ++nf)
          acc[mf][nf] = __builtin_amdgcn_mfma_f32_16x16x32_bf16(Acur[mf], Bcur[nf], acc[mf][nf], 0, 0, 0);
#pragma unroll
      for (int mf = 0; mf < 4; ++mf) Acur[mf] = Anext[mf];
#pragma unroll
      for (int nf = 0; nf < 2; ++nf) Bcur[nf] = Bnext[nf];
    }
#pragma unroll
    for (int nf = 0; nf < 2; ++nf) {
      bool valid = tg[nf] < TPRIME;
#pragma unroll
      for (int mf = 0; mf < 4; ++mf)
#pragma unroll
        for (int r = 0; r < 4; ++r) {
          float s = acc[mf][nf][r];
          float e = valid ? __expf(s) : 0.0f;
          se[mf][r] += e;
          sw[mf][r] = fmaf(e, s, sw[mf][r]);
        }
    }
  }
  // reduce over the 16 t-columns (l15 dim) within each wave
#pragma unroll
  for (int mf = 0; mf < 4; ++mf)
#pragma unroll
    for (int r = 0; r < 4; ++r) {
      float a = se[mf][r], c = sw[mf][r];
#pragma unroll
      for (int off = 1; off < 16; off <<= 1) {
        a += __shfl_xor(a, off, 64);
        c += __shfl_xor(c, off, 64);
      }
      se[mf][r] = a; sw[mf][r] = c;
    }
  __syncthreads();
  float* red = (float*)uls;   // alias: uls no longer needed
  if (l15 == 0) {
#pragma unroll
    for (int mf = 0; mf < 4; ++mf)
#pragma unroll
      for (int r = 0; r < 4; ++r) {
        int row = mf * 16 + quad * 4 + r;   // [0,64)
        red[w * ALT + row] = se[mf][r];
        red[4 * ALT + w * ALT + row] = sw[mf][r];
      }
  }
  __syncthreads();
  if (tid < ALT) {
    float a = 0.0f, c = 0.0f;
#pragma unroll
    for (int q = 0; q < 4; ++q) {
      a += red[q * ALT + tid];
      c += red[4 * ALT + q * ALT + tid];
    }
    int l = l0 + tid;
    if (l < LDIM) out[(size_t)b * LDIM + l] = c / a + fcb[l];
  }
}

extern "C" void kernel_launch(void* const* d_in, const int* in_sizes, int n_in,
                              void* d_out, int out_size, void* d_ws, size_t ws_size,
                              hipStream_t stream) {
  const int*   ids     = (const int*)d_in[0];
  const float* embed_w = (const float*)d_in[1];
  const float* conv_w  = (const float*)d_in[2];
  const float* conv_b  = (const float*)d_in[3];
  const float* U       = (const float*)d_in[4];
  const float* fc_bias = (const float*)d_in[5];
  float* out = (float*)d_out;

  unsigned char* p = (unsigned char*)d_ws;
  unsigned short* xp = (unsigned short*)p;                 p += (size_t)BATCH * TPADDED * DPAD * 2;
  unsigned short* hb = (unsigned short*)p;                 p += (size_t)BATCH * TPRIME * DPAD * 2;
  unsigned short* wT = (unsigned short*)p;                 p += (size_t)KSZ * DPAD * DPAD * 2;
  unsigned short* Ub = (unsigned short*)p;

  hipLaunchKernelGGL(gather_kernel, dim3(BATCH * TPADDED / 4), dim3(256), 0, stream,
                     ids, embed_w, xp);
  hipLaunchKernelGGL(wt_kernel, dim3(KSZ * DPAD), dim3(256), 0, stream, conv_w, wT);
  hipLaunchKernelGGL(ut_kernel, dim3(LPAD), dim3(256), 0, stream, U, Ub);
  hipLaunchKernelGGL(conv_mfma_kernel, dim3(BATCH * 33), dim3(256), 0, stream,
                     xp, wT, conv_b, hb);
  hipLaunchKernelGGL(attn_mfma_kernel, dim3(BATCH * NLB), dim3(256), 0, stream,
                     hb, Ub, fc_bias, out);
}

// Round 9
// 474.686 us; speedup vs baseline: 1.4047x; 1.4047x over previous
//
#include <hip/hip_runtime.h>

#define VOCAB   50000
#define LDIM    8921
#define DDIM    300
#define DPAD    320
#define KSZ     10
#define BATCH   8
#define TSEQ    2048
#define PADL    9
#define TPRIME  2057
#define TPADDED 2066

typedef short s8v __attribute__((ext_vector_type(8)));   // 8 x bf16 bits
typedef float f4v __attribute__((ext_vector_type(4)));

__device__ inline unsigned short f2bf(float f) {
  union { float f; unsigned u; } v; v.f = f;
  unsigned r = v.u + 0x7FFF + ((v.u >> 16) & 1);
  return (unsigned short)(r >> 16);
}

// ---- K1: embedding gather -> xp_bf16[b][tau][DPAD], zero-padded rows/cols
__global__ __launch_bounds__(256) void gather_kernel(
    const int* __restrict__ ids, const float* __restrict__ embed_w,
    unsigned short* __restrict__ xp) {
  int wid = blockIdx.x * 4 + (threadIdx.x >> 6);
  int lane = threadIdx.x & 63;
  int b = wid / TPADDED, tau = wid % TPADDED;
  bool inr = (tau >= PADL) && (tau < PADL + TSEQ);
  int row = inr ? ids[b * TSEQ + (tau - PADL)] : 0;
  const float* src = embed_w + (size_t)row * DDIM;
  unsigned short* dst = xp + ((size_t)b * TPADDED + tau) * DPAD;
  for (int j = 0; j < 5; ++j) {
    int col = j * 64 + lane;
    float v = (inr && col < DDIM) ? src[col] : 0.0f;
    dst[col] = f2bf(v);
  }
}

// ---- K2: conv weight transform -> wT[k][o][i] bf16, o/i padded to 320 with 0
__global__ __launch_bounds__(256) void wt_kernel(
    const float* __restrict__ w, unsigned short* __restrict__ wT) {
  int k = blockIdx.x / DPAD, o = blockIdx.x % DPAD;
  for (int i = threadIdx.x; i < DPAD; i += 256) {
    float v = (o < DDIM && i < DDIM) ? w[((size_t)o * DDIM + i) * KSZ + k] : 0.0f;
    wT[((size_t)k * DPAD + o) * DPAD + i] = f2bf(v);
  }
}

// ---- K3: U transform -> Ub[l][d] bf16, l padded, d padded to 320 with 0
#define LPAD 8960
__global__ __launch_bounds__(256) void ut_kernel(
    const float* __restrict__ U, unsigned short* __restrict__ Ub) {
  int l = blockIdx.x;
  for (int d = threadIdx.x; d < DPAD; d += 256) {
    float v = (l < LDIM && d < DDIM) ? U[(size_t)l * DDIM + d] : 0.0f;
    Ub[(size_t)l * DPAD + d] = f2bf(v);
  }
}

// ---- K4: conv via MFMA. h[b][t][o] bf16, relu+bias. (unchanged from R8)
#define CTN 64
#define CROWS 73          // CTN + KSZ - 1
#define CSTRIDE 336       // 0-conflict stride (verified round 7)
__global__ __launch_bounds__(256, 2) void conv_mfma_kernel(
    const unsigned short* __restrict__ xp, const unsigned short* __restrict__ wT,
    const float* __restrict__ bias, unsigned short* __restrict__ h) {
  __shared__ unsigned short xls[CROWS * CSTRIDE];   // 49056 B
  int b = blockIdx.x & 7, tb = blockIdx.x >> 3;
  int t0 = tb * CTN;
  int tid = threadIdx.x;
  {
    const unsigned short* src = xp + (size_t)b * TPADDED * DPAD;
    for (int idx = tid; idx < CROWS * (DPAD / 8); idx += 256) {
      int r = idx / 40, c8 = idx % 40;
      int tp = t0 + r;
      int4 v = make_int4(0, 0, 0, 0);
      if (tp < TPADDED) v = *(const int4*)&src[(size_t)tp * DPAD + c8 * 8];
      *(int4*)&xls[r * CSTRIDE + c8 * 8] = v;
    }
  }
  __syncthreads();
  int w = tid >> 6, lane = tid & 63;
  int l15 = lane & 15, quad = lane >> 4;
  f4v acc[5][4];
#pragma unroll
  for (int mf = 0; mf < 5; ++mf) {
    float bv[4];
#pragma unroll
    for (int r = 0; r < 4; ++r) {
      int o = w * 80 + mf * 16 + quad * 4 + r;
      bv[r] = (o < DDIM) ? bias[o] : 0.0f;
    }
#pragma unroll
    for (int nf = 0; nf < 4; ++nf) {
      acc[mf][nf][0] = bv[0]; acc[mf][nf][1] = bv[1];
      acc[mf][nf][2] = bv[2]; acc[mf][nf][3] = bv[3];
    }
  }
  s8v Acur[5], Anext[5];
#pragma unroll
  for (int mf = 0; mf < 5; ++mf)
    Acur[mf] = *(const s8v*)&wT[(size_t)(w * 80 + mf * 16 + l15) * DPAD + quad * 8];
  for (int iter = 0; iter < 100; ++iter) {
    int kc = iter / 10, it = iter % 10;
    if (iter < 99) {
      int kn = (iter + 1) / 10, itn = (iter + 1) % 10;
#pragma unroll
      for (int mf = 0; mf < 5; ++mf)
        Anext[mf] = *(const s8v*)&wT[((size_t)kn * DPAD + w * 80 + mf * 16 + l15) * DPAD + itn * 32 + quad * 8];
    }
    s8v Bv[4];
#pragma unroll
    for (int nf = 0; nf < 4; ++nf) {
      int rrow = nf * 16 + l15 + kc;
      Bv[nf] = *(const s8v*)&xls[rrow * CSTRIDE + it * 32 + quad * 8];
    }
#pragma unroll
    for (int mf = 0; mf < 5; ++mf)
#pragma unroll
      for (int nf = 0; nf < 4; ++nf)
        acc[mf][nf] = __builtin_amdgcn_mfma_f32_16x16x32_bf16(Acur[mf], Bv[nf], acc[mf][nf], 0, 0, 0);
#pragma unroll
    for (int mf = 0; mf < 5; ++mf) Acur[mf] = Anext[mf];
  }
#pragma unroll
  for (int mf = 0; mf < 5; ++mf) {
    int obase = w * 80 + mf * 16 + quad * 4;
#pragma unroll
    for (int nf = 0; nf < 4; ++nf) {
      int t = t0 + nf * 16 + l15;
      if (t < TPRIME) {
        unsigned short pk[4];
#pragma unroll
        for (int r = 0; r < 4; ++r) pk[r] = f2bf(fmaxf(acc[mf][nf][r], 0.0f));
        *(uint2*)&h[((size_t)b * TPRIME + t) * DPAD + obase] = *(uint2*)pk;
      }
    }
  }
}

// ---- K5: scores (U . h) via MFMA + fused softmax-weighted mean
// R5 structure (verified correct): 512 threads = 8 waves = 2 l-halves x 4
// t-quarters, wave tile 48l x 32t, B-prefetch. Working set ~117 regs.
// (512,2): budget ~256, LDS 64.5KB -> 2 blocks/CU x 8 waves = 4 waves/SIMD
// (2x R7's latency hiding). NOT (512,4)/(256,3+small-LDS): those collapse
// the allocator budget (R5: 64 regs, R8: 84 regs) and spill.
#define ALT 96
#define ASTRIDE 336
#define NLB 93
#define ATT 128
__global__ __launch_bounds__(512, 2) void attn_mfma_kernel(
    const unsigned short* __restrict__ h, const unsigned short* __restrict__ Ub,
    const float* __restrict__ fcb, float* __restrict__ out) {
  __shared__ unsigned short uls[ALT * ASTRIDE];   // 64512 B
  int b = blockIdx.x & 7, lb = blockIdx.x >> 3;
  int l0 = lb * ALT;
  int tid = threadIdx.x;
  {
    const unsigned short* src = Ub + (size_t)l0 * DPAD;
    for (int idx = tid; idx < ALT * (DPAD / 8); idx += 512) {
      int r = idx / 40, c8 = idx % 40;
      *(int4*)&uls[r * ASTRIDE + c8 * 8] = *(const int4*)&src[(size_t)r * DPAD + c8 * 8];
    }
  }
  __syncthreads();
  int w = tid >> 6, lane = tid & 63;
  int hw = w & 1, tq = w >> 1;          // l-half, t-quarter
  int l15 = lane & 15, quad = lane >> 4;
  int lbase = hw * 48;
  float se[3][4], sw[3][4];
#pragma unroll
  for (int mf = 0; mf < 3; ++mf)
#pragma unroll
    for (int r = 0; r < 4; ++r) { se[mf][r] = 0.0f; sw[mf][r] = 0.0f; }
  const unsigned short* hb = h + (size_t)b * TPRIME * DPAD;
  for (int t0 = 0; t0 < TPRIME; t0 += ATT) {
    int tg[2], tc[2];
#pragma unroll
    for (int nf = 0; nf < 2; ++nf) {
      tg[nf] = t0 + tq * 32 + nf * 16 + l15;
      tc[nf] = (tg[nf] < TPRIME) ? tg[nf] : (TPRIME - 1);
    }
    f4v acc[3][2];
#pragma unroll
    for (int mf = 0; mf < 3; ++mf)
#pragma unroll
      for (int nf = 0; nf < 2; ++nf) {
        acc[mf][nf][0] = 0.0f; acc[mf][nf][1] = 0.0f;
        acc[mf][nf][2] = 0.0f; acc[mf][nf][3] = 0.0f;
      }
    s8v Bcur[2], Bnext[2];
#pragma unroll
    for (int nf = 0; nf < 2; ++nf)
      Bcur[nf] = *(const s8v*)&hb[(size_t)tc[nf] * DPAD + quad * 8];
    for (int kc = 0; kc < 10; ++kc) {
      if (kc < 9) {
        int koffn = (kc + 1) * 32 + quad * 8;
#pragma unroll
        for (int nf = 0; nf < 2; ++nf)
          Bnext[nf] = *(const s8v*)&hb[(size_t)tc[nf] * DPAD + koffn];
      }
      int koff = kc * 32 + quad * 8;
#pragma unroll
      for (int mf = 0; mf < 3; ++mf) {
        s8v Av = *(const s8v*)&uls[(lbase + mf * 16 + l15) * ASTRIDE + koff];
#pragma unroll
        for (int nf = 0; nf < 2; ++nf)
          acc[mf][nf] = __builtin_amdgcn_mfma_f32_16x16x32_bf16(Av, Bcur[nf], acc[mf][nf], 0, 0, 0);
      }
#pragma unroll
      for (int nf = 0; nf < 2; ++nf) Bcur[nf] = Bnext[nf];
    }
#pragma unroll
    for (int nf = 0; nf < 2; ++nf) {
      bool valid = tg[nf] < TPRIME;
#pragma unroll
      for (int mf = 0; mf < 3; ++mf)
#pragma unroll
        for (int r = 0; r < 4; ++r) {
          float s = acc[mf][nf][r];
          float e = valid ? __expf(s) : 0.0f;
          se[mf][r] += e;
          sw[mf][r] = fmaf(e, s, sw[mf][r]);
        }
    }
  }
  // reduce over the 16 t-columns (l15 dim) within each wave
#pragma unroll
  for (int mf = 0; mf < 3; ++mf)
#pragma unroll
    for (int r = 0; r < 4; ++r) {
      float a = se[mf][r], c = sw[mf][r];
#pragma unroll
      for (int off = 1; off < 16; off <<= 1) {
        a += __shfl_xor(a, off, 64);
        c += __shfl_xor(c, off, 64);
      }
      se[mf][r] = a; sw[mf][r] = c;
    }
  __syncthreads();
  float* red = (float*)uls;   // alias: uls no longer needed
  if (l15 == 0) {
#pragma unroll
    for (int mf = 0; mf < 3; ++mf)
#pragma unroll
      for (int r = 0; r < 4; ++r) {
        int row = lbase + mf * 16 + quad * 4 + r;   // [0,96)
        red[tq * ALT + row] = se[mf][r];
        red[4 * ALT + tq * ALT + row] = sw[mf][r];
      }
  }
  __syncthreads();
  if (tid < ALT) {
    float a = 0.0f, c = 0.0f;
#pragma unroll
    for (int q = 0; q < 4; ++q) {
      a += red[q * ALT + tid];
      c += red[4 * ALT + q * ALT + tid];
    }
    int l = l0 + tid;
    if (l < LDIM) out[(size_t)b * LDIM + l] = c / a + fcb[l];
  }
}

extern "C" void kernel_launch(void* const* d_in, const int* in_sizes, int n_in,
                              void* d_out, int out_size, void* d_ws, size_t ws_size,
                              hipStream_t stream) {
  const int*   ids     = (const int*)d_in[0];
  const float* embed_w = (const float*)d_in[1];
  const float* conv_w  = (const float*)d_in[2];
  const float* conv_b  = (const float*)d_in[3];
  const float* U       = (const float*)d_in[4];
  const float* fc_bias = (const float*)d_in[5];
  float* out = (float*)d_out;

  unsigned char* p = (unsigned char*)d_ws;
  unsigned short* xp = (unsigned short*)p;                 p += (size_t)BATCH * TPADDED * DPAD * 2;
  unsigned short* hb = (unsigned short*)p;                 p += (size_t)BATCH * TPRIME * DPAD * 2;
  unsigned short* wT = (unsigned short*)p;                 p += (size_t)KSZ * DPAD * DPAD * 2;
  unsigned short* Ub = (unsigned short*)p;

  hipLaunchKernelGGL(gather_kernel, dim3(BATCH * TPADDED / 4), dim3(256), 0, stream,
                     ids, embed_w, xp);
  hipLaunchKernelGGL(wt_kernel, dim3(KSZ * DPAD), dim3(256), 0, stream, conv_w, wT);
  hipLaunchKernelGGL(ut_kernel, dim3(LPAD), dim3(256), 0, stream, U, Ub);
  hipLaunchKernelGGL(conv_mfma_kernel, dim3(BATCH * 33), dim3(256), 0, stream,
                     xp, wT, conv_b, hb);
  hipLaunchKernelGGL(attn_mfma_kernel, dim3(BATCH * NLB), dim3(512), 0, stream,
                     hb, Ub, fc_bias, out);
}